// Round 1
// baseline (1265.622 us; speedup 1.0000x reference)
//
#include <hip/hip_runtime.h>
#include <math.h>

// Problem constants
#define NN 50000
#define GG 2500
// ws layout (float offsets)
#define WS_YG    0
#define WS_SINV  36864
#define WS_FL    (WS_SINV + 19200000)
#define WS_HEL   (WS_FL + 50000)
#define WS_LPEL  (WS_HEL + 50000)
#define WS_SCOV  (WS_LPEL + 50000)
#define WS_TOTAL (WS_SCOV + 2880000)

__device__ __forceinline__ void real_sh9(float x, float y, float z, float* o) {
  const float c0 = 0.28209479177387814f;
  const float c1 = 0.4886025119029199f;
  const float ca = 1.0925484305920792f;
  const float c20 = 0.31539156525252005f;
  const float c22 = 0.5462742152960396f;
  o[0] = c0;
  o[1] = c1 * y;
  o[2] = c1 * z;
  o[3] = c1 * x;
  o[4] = ca * x * y;
  o[5] = ca * y * z;
  o[6] = c20 * (3.f * z * z - 1.f);
  o[7] = ca * x * z;
  o[8] = c22 * (x * x - y * y);
}

// Kernel 0: Y_GRID (4096 x 9). Double-precision phase reduction to match
// numpy's float64 cos/sin of the unreduced Fibonacci angle.
__global__ void k_ygrid(float* __restrict__ yg) {
  int i = blockIdx.x * blockDim.x + threadIdx.x;
  if (i >= 4096) return;
  double fr = 0.38196601125010515 * (double)i;  // (3-sqrt5)/2 : ph/(2pi)
  fr -= floor(fr);
  float ph = (float)(fr * 6.283185307179586);
  float z = 1.0f - 2.0f * ((float)i + 0.5f) * (1.0f / 4096.0f);
  float r = sqrtf(fmaxf(1.f - z * z, 0.f));
  float x = r * cosf(ph);
  float y = r * sinf(ph);
  float sh[9];
  real_sh9(x, y, z, sh);
#pragma unroll
  for (int m = 0; m < 9; ++m) yg[i * 9 + m] = sh[m];
}

// Kernel 1: per-group A = bag . W_bag, then per-node cov = A^T xs, norms -> s_inv,
// full cov stored only for the focused node.
template <int L, int COMP, int OFF>
__device__ __forceinline__ void cov_block(
    const float* __restrict__ s_inter, const float* __restrict__ Wl,
    float b0, float b1, float b2, float b3,
    int n0, int nseg, int gi, int g,
    float* __restrict__ sinv, float* __restrict__ scov, float* A) {
  const int t = threadIdx.x;
  __syncthreads();  // protect A across l iterations
  for (int idx = t; idx < 16384; idx += 256) {
    const int i = idx >> 7, o = idx & 127;
    const float* wp = Wl + i * 512 + o;
    A[i * 128 + o] = b0 * wp[0] + b1 * wp[128] + b2 * wp[256] + b3 * wp[384];
  }
  __syncthreads();
  const int slot = t >> 5;          // 8 node-slots
  const int o4 = (t & 31) << 2;     // 4 contiguous o per thread
  for (int p = slot; p < nseg; p += 8) {
    const int n = n0 + p;
    const float* xp = s_inter + (size_t)n * 1152 + OFF;
    float acc[COMP][4];
#pragma unroll
    for (int m = 0; m < COMP; ++m) {
#pragma unroll
      for (int j = 0; j < 4; ++j) acc[m][j] = 0.f;
    }
#pragma unroll 4
    for (int i = 0; i < 128; ++i) {
      const float4 a4 = *(const float4*)(A + i * 128 + o4);
#pragma unroll
      for (int m = 0; m < COMP; ++m) {
        const float xv = xp[i * COMP + m];
        acc[m][0] = fmaf(a4.x, xv, acc[m][0]);
        acc[m][1] = fmaf(a4.y, xv, acc[m][1]);
        acc[m][2] = fmaf(a4.z, xv, acc[m][2]);
        acc[m][3] = fmaf(a4.w, xv, acc[m][3]);
      }
    }
    const bool isf = (n == gi);
    const float invs = 0.044194173824159216f;  // 1/sqrt(512)
#pragma unroll
    for (int j = 0; j < 4; ++j) {
      float s = 1e-12f;
#pragma unroll
      for (int m = 0; m < COMP; ++m) {
        const float cv = acc[m][j] * invs;
        s += cv * cv;
        if (isf) scov[(size_t)g * 1152 + OFF + (o4 + j) * COMP + m] = cv;
      }
      sinv[(size_t)n * 384 + L * 128 + o4 + j] = sqrtf(s);
    }
  }
}

__global__ __launch_bounds__(256) void k_cov(
    const float* __restrict__ s_inter, const float* __restrict__ bag,
    const int* __restrict__ ptr, const int* __restrict__ focus,
    const float* __restrict__ W_bag,
    float* __restrict__ sinv, float* __restrict__ scov) {
  __shared__ __align__(16) float A[16384];  // 64 KB
  const int g = blockIdx.x;
  const int n0 = ptr[g];
  const int nseg = ptr[g + 1] - n0;
  const int gi = n0 + focus[g];
  const float b0 = bag[g * 4 + 0], b1 = bag[g * 4 + 1];
  const float b2 = bag[g * 4 + 2], b3 = bag[g * 4 + 3];
  cov_block<0, 1, 0>(s_inter, W_bag, b0, b1, b2, b3, n0, nseg, gi, g, sinv, scov, A);
  cov_block<1, 3, 128>(s_inter, W_bag + 65536, b0, b1, b2, b3, n0, nseg, gi, g, sinv, scov, A);
  cov_block<2, 5, 512>(s_inter, W_bag + 131072, b0, b1, b2, b3, n0, nseg, gi, g, sinv, scov, A);
}

// Kernel 2: the two N-wide MLPs (focus scalar fl; element logits -> probs/entropy).
// 16 nodes per 128-thread block; thread t owns hidden unit t for all 16 nodes.
__global__ __launch_bounds__(128) void k_mlp(
    const float* __restrict__ sinv, const float* __restrict__ bag,
    const int* __restrict__ batch, const int* __restrict__ element,
    const float* __restrict__ W1f, const float* __restrict__ b1f,
    const float* __restrict__ W2f, const float* __restrict__ b2f,
    const float* __restrict__ W1e, const float* __restrict__ b1e,
    const float* __restrict__ W2e, const float* __restrict__ b2e,
    float* __restrict__ flv, float* __restrict__ helv, float* __restrict__ lpelv) {
  __shared__ __align__(16) float sv[16][384];
  __shared__ float hf[16][132];
  __shared__ float he[16][132];
  __shared__ float els[16][4];
  const int t = threadIdx.x;
  const int n0 = blockIdx.x * 16;
  for (int idx = t; idx < 16 * 384; idx += 128) {
    const int p = idx / 384, c = idx - p * 384;
    sv[p][c] = sinv[(size_t)(n0 + p) * 384 + c];
  }
  __syncthreads();
  float af[16], ae[16];
#pragma unroll
  for (int p = 0; p < 16; ++p) { af[p] = 0.f; ae[p] = 0.f; }
  for (int c = 0; c < 384; c += 4) {
    const float wf0 = W1f[(c + 0) * 128 + t];
    const float wf1 = W1f[(c + 1) * 128 + t];
    const float wf2 = W1f[(c + 2) * 128 + t];
    const float wf3 = W1f[(c + 3) * 128 + t];
    const float we0 = W1e[(c + 0) * 128 + t];
    const float we1 = W1e[(c + 1) * 128 + t];
    const float we2 = W1e[(c + 2) * 128 + t];
    const float we3 = W1e[(c + 3) * 128 + t];
#pragma unroll
    for (int p = 0; p < 16; ++p) {
      const float4 s4 = *(const float4*)(&sv[p][c]);
      af[p] = fmaf(s4.x, wf0, af[p]);
      af[p] = fmaf(s4.y, wf1, af[p]);
      af[p] = fmaf(s4.z, wf2, af[p]);
      af[p] = fmaf(s4.w, wf3, af[p]);
      ae[p] = fmaf(s4.x, we0, ae[p]);
      ae[p] = fmaf(s4.y, we1, ae[p]);
      ae[p] = fmaf(s4.z, we2, ae[p]);
      ae[p] = fmaf(s4.w, we3, ae[p]);
    }
  }
  const float bf = b1f[t], be = b1e[t];
#pragma unroll
  for (int p = 0; p < 16; ++p) {
    hf[p][t] = fmaxf(af[p] + bf, 0.f);
    he[p][t] = fmaxf(ae[p] + be, 0.f);
  }
  __syncthreads();
  if (t < 80) {  // 16 nodes x (1 fl + 4 el)
    const int p = t / 5, q = t - p * 5;
    if (q == 0) {
      float s = 0.f;
      for (int j = 0; j < 128; ++j) s = fmaf(hf[p][j], W2f[j], s);
      flv[n0 + p] = s + b2f[0];
    } else {
      const int z = q - 1;
      float s = 0.f;
      for (int j = 0; j < 128; ++j) s = fmaf(he[p][j], W2e[j * 4 + z], s);
      els[p][z] = s + b2e[z];
    }
  }
  __syncthreads();
  if (t < 16) {
    const int n = n0 + t;
    const int g = batch[n];
    const int elem = element[g];
    float v[4];
#pragma unroll
    for (int z = 0; z < 4; ++z) {
      const bool mk = bag[g * 4 + z] > 0.f;
      v[z] = mk ? els[t][z] : -1e9f;
    }
    const float mx = fmaxf(fmaxf(v[0], v[1]), fmaxf(v[2], v[3]));
    float e[4];
    float S = 0.f;
#pragma unroll
    for (int z = 0; z < 4; ++z) { e[z] = expf(v[z] - mx); S += e[z]; }
    const float iS = 1.f / S;
    float h = 0.f;
#pragma unroll
    for (int z = 0; z < 4; ++z) {
      const float pz = e[z] * iS;
      h -= pz * logf(fmaxf(pz, 1e-20f));
    }
    helv[n] = h;
    lpelv[n] = logf(e[elem] * iS + 1e-20f);
  }
}

// Kernel 3: per-group epilogue.
__global__ __launch_bounds__(128) void k_group(
    const int* __restrict__ ptr, const int* __restrict__ focus,
    const int* __restrict__ element, const float* __restrict__ distance,
    const float* __restrict__ orientation, const float* __restrict__ dls,
    const float* __restrict__ W_mix,
    const float* __restrict__ W1d, const float* __restrict__ b1d,
    const float* __restrict__ W2d, const float* __restrict__ b2d,
    const float* __restrict__ flv, const float* __restrict__ helv,
    const float* __restrict__ lpelv, const float* __restrict__ sinv,
    const float* __restrict__ scov, const float* __restrict__ yg,
    float* __restrict__ out) {
  __shared__ float fls[32];
  __shared__ float hels[32];
  __shared__ __align__(16) float svg[384];
  __shared__ float hd[128];
  __shared__ float out6[6];
  __shared__ float red[128][12];
  __shared__ float conds[9];
  __shared__ float mred[128];
  __shared__ float sred[128];
  const int g = blockIdx.x;
  const int t = threadIdx.x;
  const int n0 = ptr[g];
  const int nseg = ptr[g + 1] - n0;
  const int floc = focus[g];
  const int gi = n0 + floc;
  const int elem = element[g];
  const float dist = distance[g];
  if (t < nseg) { fls[t] = flv[n0 + t]; hels[t] = helv[n0 + t]; }
  for (int c = t; c < 384; c += 128) svg[c] = sinv[(size_t)gi * 384 + c];
  __syncthreads();
  float res_lpf = 0.f, res_ent = 0.f;
  if (t == 0) {  // focus softmax + entropies (20-long serial)
    float mx = -1e30f;
    for (int p = 0; p < nseg; ++p) mx = fmaxf(mx, fls[p]);
    float S = 0.f;
    for (int p = 0; p < nseg; ++p) S += expf(fls[p] - mx);
    const float iS = 1.f / S;
    float hfoc = 0.f, hef = 0.f;
    for (int p = 0; p < nseg; ++p) {
      const float pp = expf(fls[p] - mx) * iS;
      hfoc -= pp * logf(pp + 1e-20f);
      hef += pp * hels[p];
    }
    res_lpf = logf(expf(fls[floc] - mx) * iS + 1e-20f);
    res_ent = hfoc + hef;
  }
  // d-MLP hidden: thread t = hidden unit
  {
    float acc = b1d[t];
    for (int c = 0; c < 384; c += 4) {
      const float4 s4 = *(const float4*)(&svg[c]);
      acc = fmaf(s4.x, W1d[(c + 0) * 128 + t], acc);
      acc = fmaf(s4.y, W1d[(c + 1) * 128 + t], acc);
      acc = fmaf(s4.z, W1d[(c + 2) * 128 + t], acc);
      acc = fmaf(s4.w, W1d[(c + 3) * 128 + t], acc);
    }
    acc += W1d[(384 + elem) * 128 + t];  // one-hot element tail
    hd[t] = fmaxf(acc, 0.f);
  }
  __syncthreads();
  if (t < 6) {
    float s = 0.f;
    for (int j = 0; j < 128; ++j) s = fmaf(hd[j], W2d[j * 6 + t], s);
    out6[t] = s + b2d[t];
  }
  // Bessel mix + conditional cov partials (thread t = i index)
  {
    float bess[8];
    const float sq2d = 1.0540925533894598f;  // sqrt(2/1.8)
#pragma unroll
    for (int k = 0; k < 8; ++k)
      bess[k] = sq2d * sinf((float)(k + 1) * 3.14159265358979323846f * dist / 1.8f) / dist;
    const float invnb = 0.35355339059327373f;  // 1/sqrt(8)
    float partial[9];
    {
      float tw = 0.f;
#pragma unroll
      for (int k = 0; k < 8; ++k) tw += bess[k] * W_mix[k * 1536 + t * 4 + elem];
      tw *= invnb;
      partial[0] = scov[(size_t)g * 1152 + t] * tw;
    }
    {
      float tw = 0.f;
#pragma unroll
      for (int k = 0; k < 8; ++k) tw += bess[k] * W_mix[k * 1536 + (128 + t) * 4 + elem];
      tw *= invnb;
#pragma unroll
      for (int m = 0; m < 3; ++m) partial[1 + m] = scov[(size_t)g * 1152 + 128 + t * 3 + m] * tw;
    }
    {
      float tw = 0.f;
#pragma unroll
      for (int k = 0; k < 8; ++k) tw += bess[k] * W_mix[k * 1536 + (256 + t) * 4 + elem];
      tw *= invnb;
#pragma unroll
      for (int m = 0; m < 5; ++m) partial[4 + m] = scov[(size_t)g * 1152 + 512 + t * 5 + m] * tw;
    }
#pragma unroll
    for (int q = 0; q < 9; ++q) red[t][q] = partial[q];
  }
  __syncthreads();
  if (t < 9) {
    float s = 0.f;
    for (int i = 0; i < 128; ++i) s += red[i][t];
    conds[t] = s * 0.044194173824159216f;  // /sqrt(512)
  }
  __syncthreads();
  const float c0 = conds[0], c1 = conds[1], c2 = conds[2], c3 = conds[3];
  const float c4 = conds[4], c5 = conds[5], c6 = conds[6], c7 = conds[7];
  const float c8 = conds[8];
  // spherical logsumexp over 4096 grid points (online per thread)
  float lm = -1e30f, ls = 0.f;
  for (int p = t; p < 4096; p += 128) {
    const float* yp = yg + p * 9;
    float v = c0 * yp[0] + c1 * yp[1] + c2 * yp[2] + c3 * yp[3] + c4 * yp[4] +
              c5 * yp[5] + c6 * yp[6] + c7 * yp[7] + c8 * yp[8];
    v *= 10.0f;
    if (v > lm) { ls = ls * expf(lm - v) + 1.f; lm = v; }
    else ls += expf(v - lm);
  }
  mred[t] = lm;
  sred[t] = ls;
  __syncthreads();
  if (t == 0) {
    // distance GMM
    const float l0 = out6[0], l1 = out6[1], l2 = out6[2];
    const float lmx = fmaxf(l0, fmaxf(l1, l2));
    const float lsew = lmx + logf(expf(l0 - lmx) + expf(l1 - lmx) + expf(l2 - lmx));
    float vals[3];
#pragma unroll
    for (int k = 0; k < 3; ++k) {
      const float mean = tanhf(out6[3 + k]) * 0.45f + 1.35f;
      const float sd = fmaxf(expf(dls[k]), 1e-6f);
      const float zz = (dist - mean) / sd;
      vals[k] = (out6[k] - lsew) + (-0.5f * zz * zz - logf(sd) - 0.9189385332046727f);
    }
    const float vm = fmaxf(vals[0], fmaxf(vals[1], vals[2]));
    const float lp_dist =
        vm + logf(expf(vals[0] - vm) + expf(vals[1] - vm) + expf(vals[2] - vm));
    // merge grid lse
    float Mx = -1e30f;
    for (int i = 0; i < 128; ++i) Mx = fmaxf(Mx, mred[i]);
    float S = 0.f;
    for (int i = 0; i < 128; ++i) S += sred[i] * expf(mred[i] - Mx);
    const float logZ = Mx + logf(S) - 8.317766166719343f + 2.5310242469692907f;
    // orientation term
    float ox = orientation[g * 3 + 0], oy = orientation[g * 3 + 1], oz = orientation[g * 3 + 2];
    const float inr = 1.f / sqrtf(ox * ox + oy * oy + oz * oz);
    ox *= inr; oy *= inr; oz *= inr;
    float sh[9];
    real_sh9(ox, oy, oz, sh);
    const float fx = c0 * sh[0] + c1 * sh[1] + c2 * sh[2] + c3 * sh[3] + c4 * sh[4] +
                     c5 * sh[5] + c6 * sh[6] + c7 * sh[7] + c8 * sh[8];
    const float lp_ori = 10.0f * fx - logZ;
    out[g * 2 + 0] = res_lpf + lpelv[gi] + lp_dist + lp_ori;
    out[g * 2 + 1] = res_ent;
  }
}

extern "C" void kernel_launch(void* const* d_in, const int* in_sizes, int n_in,
                              void* d_out, int out_size, void* d_ws, size_t ws_size,
                              hipStream_t stream) {
  const float* s_inter = (const float*)d_in[0];
  const float* bag = (const float*)d_in[1];
  const int* batch = (const int*)d_in[2];
  const int* ptr = (const int*)d_in[3];
  const int* focus = (const int*)d_in[4];
  const int* element = (const int*)d_in[5];
  const float* distance = (const float*)d_in[6];
  const float* orientation = (const float*)d_in[7];
  const float* W_bag = (const float*)d_in[8];
  const float* dls = (const float*)d_in[9];
  const float* W_mix = (const float*)d_in[10];
  const float* W1f = (const float*)d_in[11];
  const float* b1f = (const float*)d_in[12];
  const float* W2f = (const float*)d_in[13];
  const float* b2f = (const float*)d_in[14];
  const float* W1e = (const float*)d_in[15];
  const float* b1e = (const float*)d_in[16];
  const float* W2e = (const float*)d_in[17];
  const float* b2e = (const float*)d_in[18];
  const float* W1d = (const float*)d_in[19];
  const float* b1d = (const float*)d_in[20];
  const float* W2d = (const float*)d_in[21];
  const float* b2d = (const float*)d_in[22];

  if (ws_size < (size_t)WS_TOTAL * sizeof(float)) return;  // need ~89 MB scratch

  float* ws = (float*)d_ws;
  float* yg = ws + WS_YG;
  float* sinv = ws + WS_SINV;
  float* flv = ws + WS_FL;
  float* helv = ws + WS_HEL;
  float* lpelv = ws + WS_LPEL;
  float* scov = ws + WS_SCOV;
  float* out = (float*)d_out;

  k_ygrid<<<dim3(32), dim3(128), 0, stream>>>(yg);
  k_cov<<<dim3(GG), dim3(256), 0, stream>>>(s_inter, bag, ptr, focus, W_bag, sinv, scov);
  k_mlp<<<dim3(NN / 16), dim3(128), 0, stream>>>(sinv, bag, batch, element,
                                                 W1f, b1f, W2f, b2f,
                                                 W1e, b1e, W2e, b2e,
                                                 flv, helv, lpelv);
  k_group<<<dim3(GG), dim3(128), 0, stream>>>(ptr, focus, element, distance, orientation,
                                              dls, W_mix, W1d, b1d, W2d, b2d,
                                              flv, helv, lpelv, sinv, scov, yg, out);
}

// Round 2
// 993.973 us; speedup vs baseline: 1.2733x; 1.2733x over previous
//
#include <hip/hip_runtime.h>
#include <math.h>

// Problem constants
#define NN 50000
#define GG 2500
// ws layout (float offsets)
#define WS_YG    0
#define WS_SINV  36864
#define WS_FL    (WS_SINV + 19200000)
#define WS_HEL   (WS_FL + 50000)
#define WS_LPEL  (WS_HEL + 50000)
#define WS_SCOV  (WS_LPEL + 50000)
#define WS_TOTAL (WS_SCOV + 2880000)

__device__ __forceinline__ void real_sh9(float x, float y, float z, float* o) {
  const float c0 = 0.28209479177387814f;
  const float c1 = 0.4886025119029199f;
  const float ca = 1.0925484305920792f;
  const float c20 = 0.31539156525252005f;
  const float c22 = 0.5462742152960396f;
  o[0] = c0;
  o[1] = c1 * y;
  o[2] = c1 * z;
  o[3] = c1 * x;
  o[4] = ca * x * y;
  o[5] = ca * y * z;
  o[6] = c20 * (3.f * z * z - 1.f);
  o[7] = ca * x * z;
  o[8] = c22 * (x * x - y * y);
}

// Kernel 0: Y_GRID (4096 x 9). Double-precision phase reduction to match
// numpy's float64 cos/sin of the unreduced Fibonacci angle.
__global__ void k_ygrid(float* __restrict__ yg) {
  int i = blockIdx.x * blockDim.x + threadIdx.x;
  if (i >= 4096) return;
  double fr = 0.38196601125010515 * (double)i;  // (3-sqrt5)/2 : ph/(2pi)
  fr -= floor(fr);
  float ph = (float)(fr * 6.283185307179586);
  float z = 1.0f - 2.0f * ((float)i + 0.5f) * (1.0f / 4096.0f);
  float r = sqrtf(fmaxf(1.f - z * z, 0.f));
  float x = r * cosf(ph);
  float y = r * sinf(ph);
  float sh[9];
  real_sh9(x, y, z, sh);
#pragma unroll
  for (int m = 0; m < 9; ++m) yg[i * 9 + m] = sh[m];
}

// Kernel 1 v2: grid (G, 2) — each block handles an o-half (64 outputs).
// A-half = 128i x 64o = 32 KB LDS -> 5 blocks/CU; block = 320 threads =
// 20 node-slots x 16 o-threads (4 o each) so every node is live at once.
template <int L, int COMP, int OFF>
__device__ __forceinline__ void cov_block(
    const float* __restrict__ s_inter, const float* __restrict__ Wl,
    float b0, float b1, float b2, float b3,
    int n0, int nseg, int gi, int g, int obase,
    float* __restrict__ sinv, float* __restrict__ scov, float* A) {
  const int t = threadIdx.x;
  __syncthreads();  // protect A across l iterations
  for (int idx = t; idx < 8192; idx += 320) {
    const int i = idx >> 6, ol = idx & 63;
    const float* wp = Wl + i * 512 + obase + ol;
    A[idx] = b0 * wp[0] + b1 * wp[128] + b2 * wp[256] + b3 * wp[384];
  }
  __syncthreads();
  const int o4 = (t & 15) << 2;   // 4 contiguous local-o per thread
  const int slot = t >> 4;        // 20 node-slots
  if (slot < nseg) {
    const int n = n0 + slot;
    const float* xp = s_inter + (size_t)n * 1152 + OFF;
    float acc[COMP][4];
#pragma unroll
    for (int m = 0; m < COMP; ++m) {
#pragma unroll
      for (int j = 0; j < 4; ++j) acc[m][j] = 0.f;
    }
#pragma unroll 4
    for (int i = 0; i < 128; ++i) {
      const float4 a4 = *(const float4*)(A + i * 64 + o4);
#pragma unroll
      for (int m = 0; m < COMP; ++m) {
        const float xv = xp[i * COMP + m];
        acc[m][0] = fmaf(a4.x, xv, acc[m][0]);
        acc[m][1] = fmaf(a4.y, xv, acc[m][1]);
        acc[m][2] = fmaf(a4.z, xv, acc[m][2]);
        acc[m][3] = fmaf(a4.w, xv, acc[m][3]);
      }
    }
    const bool isf = (n == gi);
    const float invs = 0.044194173824159216f;  // 1/sqrt(512)
#pragma unroll
    for (int j = 0; j < 4; ++j) {
      const int o = obase + o4 + j;
      float s = 1e-12f;
#pragma unroll
      for (int m = 0; m < COMP; ++m) {
        const float cv = acc[m][j] * invs;
        s += cv * cv;
        if (isf) scov[(size_t)g * 1152 + OFF + o * COMP + m] = cv;
      }
      sinv[(size_t)n * 384 + L * 128 + o] = sqrtf(s);
    }
  }
}

__global__ __launch_bounds__(320) void k_cov(
    const float* __restrict__ s_inter, const float* __restrict__ bag,
    const int* __restrict__ ptr, const int* __restrict__ focus,
    const float* __restrict__ W_bag,
    float* __restrict__ sinv, float* __restrict__ scov) {
  __shared__ __align__(16) float A[8192];  // 32 KB
  const int g = blockIdx.x;
  const int obase = blockIdx.y * 64;
  const int n0 = ptr[g];
  const int nseg = ptr[g + 1] - n0;
  const int gi = n0 + focus[g];
  const float b0 = bag[g * 4 + 0], b1 = bag[g * 4 + 1];
  const float b2 = bag[g * 4 + 2], b3 = bag[g * 4 + 3];
  cov_block<0, 1, 0>(s_inter, W_bag, b0, b1, b2, b3, n0, nseg, gi, g, obase, sinv, scov, A);
  cov_block<1, 3, 128>(s_inter, W_bag + 65536, b0, b1, b2, b3, n0, nseg, gi, g, obase, sinv, scov, A);
  cov_block<2, 5, 512>(s_inter, W_bag + 131072, b0, b1, b2, b3, n0, nseg, gi, g, obase, sinv, scov, A);
}

// Kernel 2 v2: 16 nodes per 128-thread block; thread t = hidden unit t.
// s_inv staged in 64-col chunks (4 KB); after the main loop the SAME LDS
// buffer holds hidden activations at padded stride 132 (bank-conflict-free
// layer-2 dot). Total LDS ~17 KB -> ~9 blocks/CU.
__global__ __launch_bounds__(128) void k_mlp(
    const float* __restrict__ sinv, const float* __restrict__ bag,
    const int* __restrict__ batch, const int* __restrict__ element,
    const float* __restrict__ W1f, const float* __restrict__ b1f,
    const float* __restrict__ W2f, const float* __restrict__ b2f,
    const float* __restrict__ W1e, const float* __restrict__ b1e,
    const float* __restrict__ W2e, const float* __restrict__ b2e,
    float* __restrict__ flv, float* __restrict__ helv, float* __restrict__ lpelv) {
  __shared__ __align__(16) float lds[4224];  // chunk: [16][64]; later hf/he [16][132] x2
  __shared__ float els[16][4];
  const int t = threadIdx.x;
  const int n0 = blockIdx.x * 16;
  float af[16], ae[16];
#pragma unroll
  for (int p = 0; p < 16; ++p) { af[p] = 0.f; ae[p] = 0.f; }
  const float bf = b1f[t], be = b1e[t];
  for (int cb = 0; cb < 6; ++cb) {
    const int c0 = cb * 64;
    __syncthreads();
    {
      const int p = t >> 3, q = (t & 7) * 8;
      const float* src = sinv + (size_t)(n0 + p) * 384 + c0 + q;
      const float4 v0 = *(const float4*)(src);
      const float4 v1 = *(const float4*)(src + 4);
      *(float4*)(lds + p * 64 + q) = v0;
      *(float4*)(lds + p * 64 + q + 4) = v1;
    }
    __syncthreads();
    for (int cc = 0; cc < 64; cc += 4) {
      const int c = c0 + cc;
      const float wf0 = W1f[(c + 0) * 128 + t];
      const float wf1 = W1f[(c + 1) * 128 + t];
      const float wf2 = W1f[(c + 2) * 128 + t];
      const float wf3 = W1f[(c + 3) * 128 + t];
      const float we0 = W1e[(c + 0) * 128 + t];
      const float we1 = W1e[(c + 1) * 128 + t];
      const float we2 = W1e[(c + 2) * 128 + t];
      const float we3 = W1e[(c + 3) * 128 + t];
#pragma unroll
      for (int p = 0; p < 16; ++p) {
        const float4 s4 = *(const float4*)(lds + p * 64 + cc);
        af[p] = fmaf(s4.x, wf0, af[p]);
        af[p] = fmaf(s4.y, wf1, af[p]);
        af[p] = fmaf(s4.z, wf2, af[p]);
        af[p] = fmaf(s4.w, wf3, af[p]);
        ae[p] = fmaf(s4.x, we0, ae[p]);
        ae[p] = fmaf(s4.y, we1, ae[p]);
        ae[p] = fmaf(s4.z, we2, ae[p]);
        ae[p] = fmaf(s4.w, we3, ae[p]);
      }
    }
  }
  __syncthreads();
#pragma unroll
  for (int p = 0; p < 16; ++p) {
    lds[p * 132 + t] = fmaxf(af[p] + bf, 0.f);          // hf
    lds[2112 + p * 132 + t] = fmaxf(ae[p] + be, 0.f);   // he
  }
  __syncthreads();
  if (t < 80) {  // 16 nodes x (1 fl + 4 el)
    const int p = t / 5, q = t - p * 5;
    if (q == 0) {
      float s = 0.f;
      for (int j = 0; j < 128; ++j) s = fmaf(lds[p * 132 + j], W2f[j], s);
      flv[n0 + p] = s + b2f[0];
    } else {
      const int z = q - 1;
      float s = 0.f;
      for (int j = 0; j < 128; ++j) s = fmaf(lds[2112 + p * 132 + j], W2e[j * 4 + z], s);
      els[p][z] = s + b2e[z];
    }
  }
  __syncthreads();
  if (t < 16) {
    const int n = n0 + t;
    const int g = batch[n];
    const int elem = element[g];
    float v[4];
#pragma unroll
    for (int z = 0; z < 4; ++z) {
      const bool mk = bag[g * 4 + z] > 0.f;
      v[z] = mk ? els[t][z] : -1e9f;
    }
    const float mx = fmaxf(fmaxf(v[0], v[1]), fmaxf(v[2], v[3]));
    float e[4];
    float S = 0.f;
#pragma unroll
    for (int z = 0; z < 4; ++z) { e[z] = expf(v[z] - mx); S += e[z]; }
    const float iS = 1.f / S;
    float h = 0.f;
#pragma unroll
    for (int z = 0; z < 4; ++z) {
      const float pz = e[z] * iS;
      h -= pz * logf(fmaxf(pz, 1e-20f));
    }
    helv[n] = h;
    lpelv[n] = logf(e[elem] * iS + 1e-20f);
  }
}

// Kernel 3: per-group epilogue.
__global__ __launch_bounds__(128) void k_group(
    const int* __restrict__ ptr, const int* __restrict__ focus,
    const int* __restrict__ element, const float* __restrict__ distance,
    const float* __restrict__ orientation, const float* __restrict__ dls,
    const float* __restrict__ W_mix,
    const float* __restrict__ W1d, const float* __restrict__ b1d,
    const float* __restrict__ W2d, const float* __restrict__ b2d,
    const float* __restrict__ flv, const float* __restrict__ helv,
    const float* __restrict__ lpelv, const float* __restrict__ sinv,
    const float* __restrict__ scov, const float* __restrict__ yg,
    float* __restrict__ out) {
  __shared__ float fls[32];
  __shared__ float hels[32];
  __shared__ __align__(16) float svg[384];
  __shared__ float hd[128];
  __shared__ float out6[6];
  __shared__ float red[128][12];
  __shared__ float conds[9];
  __shared__ float mred[128];
  __shared__ float sred[128];
  const int g = blockIdx.x;
  const int t = threadIdx.x;
  const int n0 = ptr[g];
  const int nseg = ptr[g + 1] - n0;
  const int floc = focus[g];
  const int gi = n0 + floc;
  const int elem = element[g];
  const float dist = distance[g];
  if (t < nseg) { fls[t] = flv[n0 + t]; hels[t] = helv[n0 + t]; }
  for (int c = t; c < 384; c += 128) svg[c] = sinv[(size_t)gi * 384 + c];
  __syncthreads();
  float res_lpf = 0.f, res_ent = 0.f;
  if (t == 0) {  // focus softmax + entropies (20-long serial)
    float mx = -1e30f;
    for (int p = 0; p < nseg; ++p) mx = fmaxf(mx, fls[p]);
    float S = 0.f;
    for (int p = 0; p < nseg; ++p) S += expf(fls[p] - mx);
    const float iS = 1.f / S;
    float hfoc = 0.f, hef = 0.f;
    for (int p = 0; p < nseg; ++p) {
      const float pp = expf(fls[p] - mx) * iS;
      hfoc -= pp * logf(pp + 1e-20f);
      hef += pp * hels[p];
    }
    res_lpf = logf(expf(fls[floc] - mx) * iS + 1e-20f);
    res_ent = hfoc + hef;
  }
  // d-MLP hidden: thread t = hidden unit
  {
    float acc = b1d[t];
    for (int c = 0; c < 384; c += 4) {
      const float4 s4 = *(const float4*)(&svg[c]);
      acc = fmaf(s4.x, W1d[(c + 0) * 128 + t], acc);
      acc = fmaf(s4.y, W1d[(c + 1) * 128 + t], acc);
      acc = fmaf(s4.z, W1d[(c + 2) * 128 + t], acc);
      acc = fmaf(s4.w, W1d[(c + 3) * 128 + t], acc);
    }
    acc += W1d[(384 + elem) * 128 + t];  // one-hot element tail
    hd[t] = fmaxf(acc, 0.f);
  }
  __syncthreads();
  if (t < 6) {
    float s = 0.f;
    for (int j = 0; j < 128; ++j) s = fmaf(hd[j], W2d[j * 6 + t], s);
    out6[t] = s + b2d[t];
  }
  // Bessel mix + conditional cov partials (thread t = i index)
  {
    float bess[8];
    const float sq2d = 1.0540925533894598f;  // sqrt(2/1.8)
#pragma unroll
    for (int k = 0; k < 8; ++k)
      bess[k] = sq2d * sinf((float)(k + 1) * 3.14159265358979323846f * dist / 1.8f) / dist;
    const float invnb = 0.35355339059327373f;  // 1/sqrt(8)
    float partial[9];
    {
      float tw = 0.f;
#pragma unroll
      for (int k = 0; k < 8; ++k) tw += bess[k] * W_mix[k * 1536 + t * 4 + elem];
      tw *= invnb;
      partial[0] = scov[(size_t)g * 1152 + t] * tw;
    }
    {
      float tw = 0.f;
#pragma unroll
      for (int k = 0; k < 8; ++k) tw += bess[k] * W_mix[k * 1536 + (128 + t) * 4 + elem];
      tw *= invnb;
#pragma unroll
      for (int m = 0; m < 3; ++m) partial[1 + m] = scov[(size_t)g * 1152 + 128 + t * 3 + m] * tw;
    }
    {
      float tw = 0.f;
#pragma unroll
      for (int k = 0; k < 8; ++k) tw += bess[k] * W_mix[k * 1536 + (256 + t) * 4 + elem];
      tw *= invnb;
#pragma unroll
      for (int m = 0; m < 5; ++m) partial[4 + m] = scov[(size_t)g * 1152 + 512 + t * 5 + m] * tw;
    }
#pragma unroll
    for (int q = 0; q < 9; ++q) red[t][q] = partial[q];
  }
  __syncthreads();
  if (t < 9) {
    float s = 0.f;
    for (int i = 0; i < 128; ++i) s += red[i][t];
    conds[t] = s * 0.044194173824159216f;  // /sqrt(512)
  }
  __syncthreads();
  const float c0 = conds[0], c1 = conds[1], c2 = conds[2], c3 = conds[3];
  const float c4 = conds[4], c5 = conds[5], c6 = conds[6], c7 = conds[7];
  const float c8 = conds[8];
  // spherical logsumexp over 4096 grid points (online per thread)
  float lm = -1e30f, ls = 0.f;
  for (int p = t; p < 4096; p += 128) {
    const float* yp = yg + p * 9;
    float v = c0 * yp[0] + c1 * yp[1] + c2 * yp[2] + c3 * yp[3] + c4 * yp[4] +
              c5 * yp[5] + c6 * yp[6] + c7 * yp[7] + c8 * yp[8];
    v *= 10.0f;
    if (v > lm) { ls = ls * expf(lm - v) + 1.f; lm = v; }
    else ls += expf(v - lm);
  }
  mred[t] = lm;
  sred[t] = ls;
  __syncthreads();
  if (t == 0) {
    // distance GMM
    const float l0 = out6[0], l1 = out6[1], l2 = out6[2];
    const float lmx = fmaxf(l0, fmaxf(l1, l2));
    const float lsew = lmx + logf(expf(l0 - lmx) + expf(l1 - lmx) + expf(l2 - lmx));
    float vals[3];
#pragma unroll
    for (int k = 0; k < 3; ++k) {
      const float mean = tanhf(out6[3 + k]) * 0.45f + 1.35f;
      const float sd = fmaxf(expf(dls[k]), 1e-6f);
      const float zz = (dist - mean) / sd;
      vals[k] = (out6[k] - lsew) + (-0.5f * zz * zz - logf(sd) - 0.9189385332046727f);
    }
    const float vm = fmaxf(vals[0], fmaxf(vals[1], vals[2]));
    const float lp_dist =
        vm + logf(expf(vals[0] - vm) + expf(vals[1] - vm) + expf(vals[2] - vm));
    // merge grid lse
    float Mx = -1e30f;
    for (int i = 0; i < 128; ++i) Mx = fmaxf(Mx, mred[i]);
    float S = 0.f;
    for (int i = 0; i < 128; ++i) S += sred[i] * expf(mred[i] - Mx);
    const float logZ = Mx + logf(S) - 8.317766166719343f + 2.5310242469692907f;
    // orientation term
    float ox = orientation[g * 3 + 0], oy = orientation[g * 3 + 1], oz = orientation[g * 3 + 2];
    const float inr = 1.f / sqrtf(ox * ox + oy * oy + oz * oz);
    ox *= inr; oy *= inr; oz *= inr;
    float sh[9];
    real_sh9(ox, oy, oz, sh);
    const float fx = c0 * sh[0] + c1 * sh[1] + c2 * sh[2] + c3 * sh[3] + c4 * sh[4] +
                     c5 * sh[5] + c6 * sh[6] + c7 * sh[7] + c8 * sh[8];
    const float lp_ori = 10.0f * fx - logZ;
    out[g * 2 + 0] = res_lpf + lpelv[gi] + lp_dist + lp_ori;
    out[g * 2 + 1] = res_ent;
  }
}

extern "C" void kernel_launch(void* const* d_in, const int* in_sizes, int n_in,
                              void* d_out, int out_size, void* d_ws, size_t ws_size,
                              hipStream_t stream) {
  const float* s_inter = (const float*)d_in[0];
  const float* bag = (const float*)d_in[1];
  const int* batch = (const int*)d_in[2];
  const int* ptr = (const int*)d_in[3];
  const int* focus = (const int*)d_in[4];
  const int* element = (const int*)d_in[5];
  const float* distance = (const float*)d_in[6];
  const float* orientation = (const float*)d_in[7];
  const float* W_bag = (const float*)d_in[8];
  const float* dls = (const float*)d_in[9];
  const float* W_mix = (const float*)d_in[10];
  const float* W1f = (const float*)d_in[11];
  const float* b1f = (const float*)d_in[12];
  const float* W2f = (const float*)d_in[13];
  const float* b2f = (const float*)d_in[14];
  const float* W1e = (const float*)d_in[15];
  const float* b1e = (const float*)d_in[16];
  const float* W2e = (const float*)d_in[17];
  const float* b2e = (const float*)d_in[18];
  const float* W1d = (const float*)d_in[19];
  const float* b1d = (const float*)d_in[20];
  const float* W2d = (const float*)d_in[21];
  const float* b2d = (const float*)d_in[22];

  if (ws_size < (size_t)WS_TOTAL * sizeof(float)) return;  // need ~89 MB scratch

  float* ws = (float*)d_ws;
  float* yg = ws + WS_YG;
  float* sinv = ws + WS_SINV;
  float* flv = ws + WS_FL;
  float* helv = ws + WS_HEL;
  float* lpelv = ws + WS_LPEL;
  float* scov = ws + WS_SCOV;
  float* out = (float*)d_out;

  k_ygrid<<<dim3(32), dim3(128), 0, stream>>>(yg);
  k_cov<<<dim3(GG, 2), dim3(320), 0, stream>>>(s_inter, bag, ptr, focus, W_bag, sinv, scov);
  k_mlp<<<dim3(NN / 16), dim3(128), 0, stream>>>(sinv, bag, batch, element,
                                                 W1f, b1f, W2f, b2f,
                                                 W1e, b1e, W2e, b2e,
                                                 flv, helv, lpelv);
  k_group<<<dim3(GG), dim3(128), 0, stream>>>(ptr, focus, element, distance, orientation,
                                              dls, W_mix, W1d, b1d, W2d, b2d,
                                              flv, helv, lpelv, sinv, scov, yg, out);
}